// Round 6
// baseline (532.209 us; speedup 1.0000x reference)
//
#include <hip/hip_runtime.h>

typedef short v8s __attribute__((ext_vector_type(8)));
typedef _Float16 v8h __attribute__((ext_vector_type(8)));
typedef float v4f __attribute__((ext_vector_type(4)));

typedef __attribute__((address_space(1))) const void* as1_void_cp;
typedef __attribute__((address_space(3))) void* as3_void_p;

__device__ __forceinline__ unsigned short f2bf(float x) {
  union { float f; unsigned int u; } v; v.f = x;
  unsigned int r = v.u + 0x7fffu + ((v.u >> 16) & 1u);
  return (unsigned short)(r >> 16);
}
__device__ __forceinline__ float bf2f(unsigned short h) {
  union { unsigned int u; float f; } v; v.u = ((unsigned int)h) << 16;
  return v.f;
}
__device__ __forceinline__ unsigned short f2h(float x) {
  _Float16 h = (_Float16)x;  // RTE
  return __builtin_bit_cast(unsigned short, h);
}

// ---------------------------------------------------------------------------
// Plain GEMM (bf16 or fp16 per F16): C[MxN](f32) = A[MxK] @ B[NxK]^T.
// 128x128 tile, BK=32, 256 thr. Split-K via blockIdx.z.
// ---------------------------------------------------------------------------
template <bool ADD, bool F16>
__global__ __launch_bounds__(256) void gemm_bt(
    const unsigned short* __restrict__ A, const unsigned short* __restrict__ B,
    float* __restrict__ C, const float* __restrict__ Cadd,
    int N, int lda, int ldb, int klen, size_t csplit) {
  __shared__ __align__(16) unsigned short As[128 * 32];
  __shared__ __align__(16) unsigned short Bs[128 * 32];
  const int tid = threadIdx.x;
  const int bn = blockIdx.x * 128, bm = blockIdx.y * 128;
  const int k0 = blockIdx.z * klen;
  float* Cp = C + (size_t)blockIdx.z * csplit;

  const unsigned short* ag0 = A + (size_t)(bm + (tid >> 2)) * lda + ((tid & 3) << 3) + k0;
  const unsigned short* ag1 = ag0 + (size_t)64 * lda;
  const unsigned short* bg0 = B + (size_t)(bn + (tid >> 2)) * ldb + ((tid & 3) << 3) + k0;
  const unsigned short* bg1 = bg0 + (size_t)64 * ldb;
  unsigned short* al0 = As + tid * 8;
  unsigned short* al1 = As + 2048 + tid * 8;
  unsigned short* bl0 = Bs + tid * 8;
  unsigned short* bl1 = Bs + 2048 + tid * 8;

  const int lane = tid & 63;
  const int q = lane >> 4, m15 = lane & 15;
  const int w = tid >> 6;
  const int wr = (w >> 1) * 64, wc = (w & 1) * 64;

  v4f acc[4][4];
#pragma unroll
  for (int i = 0; i < 4; ++i)
#pragma unroll
    for (int j = 0; j < 4; ++j) acc[i][j] = 0.f;

  for (int kk = 0; kk < klen; kk += 32) {
    __builtin_amdgcn_global_load_lds((as1_void_cp)(ag0 + kk), (as3_void_p)al0, 16, 0, 0);
    __builtin_amdgcn_global_load_lds((as1_void_cp)(ag1 + kk), (as3_void_p)al1, 16, 0, 0);
    __builtin_amdgcn_global_load_lds((as1_void_cp)(bg0 + kk), (as3_void_p)bl0, 16, 0, 0);
    __builtin_amdgcn_global_load_lds((as1_void_cp)(bg1 + kk), (as3_void_p)bl1, 16, 0, 0);
    __syncthreads();
    v8s af[4], bf[4];
#pragma unroll
    for (int i = 0; i < 4; ++i)
      af[i] = *(const v8s*)(As + (wr + i * 16 + m15) * 32 + q * 8);
#pragma unroll
    for (int j = 0; j < 4; ++j)
      bf[j] = *(const v8s*)(Bs + (wc + j * 16 + m15) * 32 + q * 8);
#pragma unroll
    for (int i = 0; i < 4; ++i)
#pragma unroll
      for (int j = 0; j < 4; ++j) {
        if constexpr (F16)
          acc[i][j] = __builtin_amdgcn_mfma_f32_16x16x32_f16(
              __builtin_bit_cast(v8h, af[i]), __builtin_bit_cast(v8h, bf[j]), acc[i][j], 0, 0, 0);
        else
          acc[i][j] = __builtin_amdgcn_mfma_f32_16x16x32_bf16(af[i], bf[j], acc[i][j], 0, 0, 0);
      }
    __syncthreads();
  }

#pragma unroll
  for (int i = 0; i < 4; ++i) {
#pragma unroll
    for (int j = 0; j < 4; ++j) {
      const int col = bn + wc + j * 16 + m15;
#pragma unroll
      for (int rr = 0; rr < 4; ++rr) {
        const int row = bm + wr + i * 16 + q * 4 + rr;
        const size_t idx = (size_t)row * N + col;
        float v = acc[i][j][rr];
        if (ADD) v += Cadd[idx];
        Cp[idx] = v;
      }
    }
  }
}

// ---------------------------------------------------------------------------
// Split-bf16 (compensated) GEMM: C = (Ah+Al)@(Bh+Bl)^T dropping Al*Bl.
// Used only for EM iteration 1 (largest error amplification).
// ---------------------------------------------------------------------------
__global__ __launch_bounds__(256) void gemm_bt3(
    const unsigned short* __restrict__ Ah, const unsigned short* __restrict__ Al,
    const unsigned short* __restrict__ Bh, const unsigned short* __restrict__ Bl,
    float* __restrict__ C, int N, int lda, int ldb, int klen, size_t csplit) {
  __shared__ __align__(16) unsigned short Ash[128 * 32];
  __shared__ __align__(16) unsigned short Asl[128 * 32];
  __shared__ __align__(16) unsigned short Bsh[128 * 32];
  __shared__ __align__(16) unsigned short Bsl[128 * 32];
  const int tid = threadIdx.x;
  const int bn = blockIdx.x * 128, bm = blockIdx.y * 128;
  const int k0 = blockIdx.z * klen;
  float* Cp = C + (size_t)blockIdx.z * csplit;

  const size_t aoff = (size_t)(bm + (tid >> 2)) * lda + ((tid & 3) << 3) + k0;
  const size_t boff = (size_t)(bn + (tid >> 2)) * ldb + ((tid & 3) << 3) + k0;
  const unsigned short* agh0 = Ah + aoff;
  const unsigned short* agh1 = agh0 + (size_t)64 * lda;
  const unsigned short* agl0 = Al + aoff;
  const unsigned short* agl1 = agl0 + (size_t)64 * lda;
  const unsigned short* bgh0 = Bh + boff;
  const unsigned short* bgh1 = bgh0 + (size_t)64 * ldb;
  const unsigned short* bgl0 = Bl + boff;
  const unsigned short* bgl1 = bgl0 + (size_t)64 * ldb;

  const int lane = tid & 63;
  const int q = lane >> 4, m15 = lane & 15;
  const int w = tid >> 6;
  const int wr = (w >> 1) * 64, wc = (w & 1) * 64;

  v4f acc[4][4];
#pragma unroll
  for (int i = 0; i < 4; ++i)
#pragma unroll
    for (int j = 0; j < 4; ++j) acc[i][j] = 0.f;

  for (int kk = 0; kk < klen; kk += 32) {
    __builtin_amdgcn_global_load_lds((as1_void_cp)(agh0 + kk), (as3_void_p)(Ash + tid * 8), 16, 0, 0);
    __builtin_amdgcn_global_load_lds((as1_void_cp)(agh1 + kk), (as3_void_p)(Ash + 2048 + tid * 8), 16, 0, 0);
    __builtin_amdgcn_global_load_lds((as1_void_cp)(agl0 + kk), (as3_void_p)(Asl + tid * 8), 16, 0, 0);
    __builtin_amdgcn_global_load_lds((as1_void_cp)(agl1 + kk), (as3_void_p)(Asl + 2048 + tid * 8), 16, 0, 0);
    __builtin_amdgcn_global_load_lds((as1_void_cp)(bgh0 + kk), (as3_void_p)(Bsh + tid * 8), 16, 0, 0);
    __builtin_amdgcn_global_load_lds((as1_void_cp)(bgh1 + kk), (as3_void_p)(Bsh + 2048 + tid * 8), 16, 0, 0);
    __builtin_amdgcn_global_load_lds((as1_void_cp)(bgl0 + kk), (as3_void_p)(Bsl + tid * 8), 16, 0, 0);
    __builtin_amdgcn_global_load_lds((as1_void_cp)(bgl1 + kk), (as3_void_p)(Bsl + 2048 + tid * 8), 16, 0, 0);
    __syncthreads();
    v8s afh[4], afl[4], bfh[4], bfl[4];
#pragma unroll
    for (int i = 0; i < 4; ++i) {
      const int ro = (wr + i * 16 + m15) * 32 + q * 8;
      afh[i] = *(const v8s*)(Ash + ro);
      afl[i] = *(const v8s*)(Asl + ro);
    }
#pragma unroll
    for (int j = 0; j < 4; ++j) {
      const int ro = (wc + j * 16 + m15) * 32 + q * 8;
      bfh[j] = *(const v8s*)(Bsh + ro);
      bfl[j] = *(const v8s*)(Bsl + ro);
    }
#pragma unroll
    for (int i = 0; i < 4; ++i)
#pragma unroll
      for (int j = 0; j < 4; ++j) {
        acc[i][j] = __builtin_amdgcn_mfma_f32_16x16x32_bf16(afh[i], bfh[j], acc[i][j], 0, 0, 0);
        acc[i][j] = __builtin_amdgcn_mfma_f32_16x16x32_bf16(afh[i], bfl[j], acc[i][j], 0, 0, 0);
        acc[i][j] = __builtin_amdgcn_mfma_f32_16x16x32_bf16(afl[i], bfh[j], acc[i][j], 0, 0, 0);
      }
    __syncthreads();
  }

#pragma unroll
  for (int i = 0; i < 4; ++i) {
#pragma unroll
    for (int j = 0; j < 4; ++j) {
      const int col = bn + wc + j * 16 + m15;
#pragma unroll
      for (int rr = 0; rr < 4; ++rr) {
        const int row = bm + wr + i * 16 + q * 4 + rr;
        Cp[(size_t)row * N + col] = acc[i][j][rr];
      }
    }
  }
}

// cls f32 [8192][1024] -> hi/lo bf16 row-major + hi/lo bf16 transposed
__global__ __launch_bounds__(256) void cast_split_transpose_cls(
    const float* __restrict__ cls,
    unsigned short* __restrict__ ch, unsigned short* __restrict__ cl,
    unsigned short* __restrict__ cTh, unsigned short* __restrict__ cTl) {
  __shared__ unsigned short th[64][72];
  __shared__ unsigned short tl[64][72];
  const int d0 = blockIdx.x * 64, b0 = blockIdx.y * 64;
  const int t = threadIdx.x;
#pragma unroll
  for (int i = 0; i < 4; ++i) {
    int flat = t + i * 256;
    int bl_ = flat >> 4;
    int dl = (flat & 15) << 2;
    float4 v = *(const float4*)(cls + (size_t)(b0 + bl_) * 1024 + d0 + dl);
    ushort4 h, l;
    h.x = f2bf(v.x); l.x = f2bf(v.x - bf2f(h.x));
    h.y = f2bf(v.y); l.y = f2bf(v.y - bf2f(h.y));
    h.z = f2bf(v.z); l.z = f2bf(v.z - bf2f(h.z));
    h.w = f2bf(v.w); l.w = f2bf(v.w - bf2f(h.w));
    *(ushort4*)(ch + (size_t)(b0 + bl_) * 1024 + d0 + dl) = h;
    *(ushort4*)(cl + (size_t)(b0 + bl_) * 1024 + d0 + dl) = l;
    th[bl_][dl] = h.x; th[bl_][dl + 1] = h.y; th[bl_][dl + 2] = h.z; th[bl_][dl + 3] = h.w;
    tl[bl_][dl] = l.x; tl[bl_][dl + 1] = l.y; tl[bl_][dl + 2] = l.z; tl[bl_][dl + 3] = l.w;
  }
  __syncthreads();
#pragma unroll
  for (int i = 0; i < 4; ++i) {
    int flat = t + i * 256;
    int dl = flat >> 4;
    int bl_ = (flat & 15) << 2;
    ushort4 h = make_ushort4(th[bl_][dl], th[bl_ + 1][dl], th[bl_ + 2][dl], th[bl_ + 3][dl]);
    ushort4 l = make_ushort4(tl[bl_][dl], tl[bl_ + 1][dl], tl[bl_ + 2][dl], tl[bl_ + 3][dl]);
    *(ushort4*)(cTh + (size_t)(d0 + dl) * 8192 + b0 + bl_) = h;
    *(ushort4*)(cTl + (size_t)(d0 + dl) * 8192 + b0 + bl_) = l;
  }
}

// f32 -> hi/lo bf16
__global__ __launch_bounds__(256) void split_f32(const float* __restrict__ in,
                                                 unsigned short* __restrict__ hi,
                                                 unsigned short* __restrict__ lo) {
  const size_t i = (size_t)(blockIdx.x * blockDim.x + threadIdx.x) * 4;
  float4 v = *(const float4*)(in + i);
  ushort4 h, l;
  h.x = f2bf(v.x); l.x = f2bf(v.x - bf2f(h.x));
  h.y = f2bf(v.y); l.y = f2bf(v.y - bf2f(h.y));
  h.z = f2bf(v.z); l.z = f2bf(v.z - bf2f(h.z));
  h.w = f2bf(v.w); l.w = f2bf(v.w - bf2f(h.w));
  *(ushort4*)(hi + i) = h;
  *(ushort4*)(lo + i) = l;
}

// bf16 hi+lo -> fp16, in-place capable (out may alias lo). 8 elems/thread.
__global__ __launch_bounds__(256) void fuse_to_f16(const unsigned short* __restrict__ hi,
                                                   const unsigned short* __restrict__ lo,
                                                   unsigned short* __restrict__ out) {
  const size_t i = (size_t)(blockIdx.x * blockDim.x + threadIdx.x) * 8;
  ushort4 h0 = *(const ushort4*)(hi + i);
  ushort4 h1 = *(const ushort4*)(hi + i + 4);
  ushort4 l0 = *(const ushort4*)(lo + i);
  ushort4 l1 = *(const ushort4*)(lo + i + 4);
  ushort4 o0, o1;
  o0.x = f2h(bf2f(h0.x) + bf2f(l0.x)); o0.y = f2h(bf2f(h0.y) + bf2f(l0.y));
  o0.z = f2h(bf2f(h0.z) + bf2f(l0.z)); o0.w = f2h(bf2f(h0.w) + bf2f(l0.w));
  o1.x = f2h(bf2f(h1.x) + bf2f(l1.x)); o1.y = f2h(bf2f(h1.y) + bf2f(l1.y));
  o1.z = f2h(bf2f(h1.z) + bf2f(l1.z)); o1.w = f2h(bf2f(h1.w) + bf2f(l1.w));
  *(ushort4*)(out + i) = o0;
  *(ushort4*)(out + i + 4) = o1;
}

// ---------------------------------------------------------------------------
// Fused column softmax over ST = SP0+SP1 ([c=512][b=8192] f32): one global
// read (staged in LDS), per-column max/sum, one global write.
// Block = 16 columns x all 512 rows; grid 512 blocks (2/CU).
// LDS tile bank pattern: (16c+b)%32 -> each bank hit 2x per wave64 (free).
// ---------------------------------------------------------------------------
template <bool F16>
__global__ __launch_bounds__(256) void colsoftmax_fused(
    const float* __restrict__ SP0, const float* __restrict__ SP1,
    unsigned short* __restrict__ rh, unsigned short* __restrict__ rl) {
  __shared__ float tile[512 * 16];       // 32 KB
  __shared__ float redm[16][17], reds[16][17];
  __shared__ float bm[16], bs[16];
  const int t = threadIdx.x;
  const int bl = t & 15;                 // local column
  const int j = t >> 4;                  // row-stripe 0..15
  const int bg = blockIdx.x * 16 + bl;
  float m = -3.4e38f, s = 0.f;
#pragma unroll 8
  for (int p = 0; p < 32; ++p) {
    const int c = j + (p << 4);
    const size_t idx = (size_t)c * 8192 + bg;
    const float v = SP0[idx] + SP1[idx];
    tile[c * 16 + bl] = v;
    const float nm = fmaxf(m, v);
    s = s * __expf(m - nm) + __expf(v - nm);
    m = nm;
  }
  redm[j][bl] = m; reds[j][bl] = s;
  __syncthreads();
  if (t < 16) {
    float mm = redm[0][t], ssum = reds[0][t];
#pragma unroll
    for (int k = 1; k < 16; ++k) {
      const float m2 = redm[k][t], s2 = reds[k][t];
      const float nm = fmaxf(mm, m2);
      ssum = ssum * __expf(mm - nm) + s2 * __expf(m2 - nm);
      mm = nm;
    }
    bm[t] = mm; bs[t] = 1.f / ssum;
  }
  __syncthreads();
  const float mcol = bm[bl], inv = bs[bl];
#pragma unroll 8
  for (int p = 0; p < 32; ++p) {
    const int c = j + (p << 4);
    const float r = __expf(tile[c * 16 + bl] - mcol) * inv;
    const size_t idx = (size_t)c * 8192 + bg;
    if constexpr (F16) {
      rh[idx] = f2h(r);
    } else {
      const unsigned short h0 = f2bf(r);
      rh[idx] = h0;
      rl[idx] = f2bf(r - bf2f(h0));
    }
  }
}

// Final: row softmax of SP0+SP1 [8192][512] -> r f32 (d_out) + r fp16.
__global__ __launch_bounds__(256) void softmax_rows(const float* __restrict__ SP0,
                                                    const float* __restrict__ SP1,
                                                    float* __restrict__ r_out,
                                                    unsigned short* __restrict__ r_g) {
  const int w = threadIdx.x >> 6, lane = threadIdx.x & 63;
  const int row = blockIdx.x * 4 + w;
  const size_t off = (size_t)row * 512 + lane * 8;
  float4 v0 = *(const float4*)(SP0 + off);
  float4 v1 = *(const float4*)(SP0 + off + 4);
  float4 u0 = *(const float4*)(SP1 + off);
  float4 u1 = *(const float4*)(SP1 + off + 4);
  v0.x += u0.x; v0.y += u0.y; v0.z += u0.z; v0.w += u0.w;
  v1.x += u1.x; v1.y += u1.y; v1.z += u1.z; v1.w += u1.w;
  float m = fmaxf(fmaxf(fmaxf(v0.x, v0.y), fmaxf(v0.z, v0.w)),
                  fmaxf(fmaxf(v1.x, v1.y), fmaxf(v1.z, v1.w)));
  for (int off2 = 32; off2; off2 >>= 1) m = fmaxf(m, __shfl_xor(m, off2));
  float e0 = __expf(v0.x - m), e1 = __expf(v0.y - m), e2 = __expf(v0.z - m), e3 = __expf(v0.w - m);
  float e4 = __expf(v1.x - m), e5 = __expf(v1.y - m), e6 = __expf(v1.z - m), e7 = __expf(v1.w - m);
  float s = e0 + e1 + e2 + e3 + e4 + e5 + e6 + e7;
  for (int off2 = 32; off2; off2 >>= 1) s += __shfl_xor(s, off2);
  const float inv = 1.f / s;
  e0 *= inv; e1 *= inv; e2 *= inv; e3 *= inv; e4 *= inv; e5 *= inv; e6 *= inv; e7 *= inv;
  float* rp = r_out + off;
  *(float4*)rp = make_float4(e0, e1, e2, e3);
  *(float4*)(rp + 4) = make_float4(e4, e5, e6, e7);
  unsigned short* bp = r_g + off;
  *(ushort4*)bp = make_ushort4(f2h(e0), f2h(e1), f2h(e2), f2h(e3));
  *(ushort4*)(bp + 4) = make_ushort4(f2h(e4), f2h(e5), f2h(e6), f2h(e7));
}

// Sum 16 split-K partials [512][1024], L2-normalize rows (+1e-6),
// emit p fp16 [512][1024] + pT fp16 [1024][512].
__global__ __launch_bounds__(256) void reduce_normalize(const float* __restrict__ Pp,
                                                        unsigned short* __restrict__ pg,
                                                        unsigned short* __restrict__ pTg) {
  __shared__ float red[4];
  const int c = blockIdx.x, t = threadIdx.x;
  float ax = 0.f, ay = 0.f, az = 0.f, aw = 0.f;
#pragma unroll
  for (int s = 0; s < 16; ++s) {
    const float4 v = *(const float4*)(Pp + ((size_t)s * 512 + c) * 1024 + t * 4);
    ax += v.x; ay += v.y; az += v.z; aw += v.w;
  }
  float ss = ax * ax + ay * ay + az * az + aw * aw;
  for (int off = 32; off; off >>= 1) ss += __shfl_xor(ss, off);
  const int w = t >> 6, lane = t & 63;
  if (!lane) red[w] = ss;
  __syncthreads();
  const float tot = red[0] + red[1] + red[2] + red[3];
  const float scale = 1.f / (sqrtf(tot) + 1e-6f);
  ax *= scale; ay *= scale; az *= scale; aw *= scale;
  *(ushort4*)(pg + (size_t)c * 1024 + t * 4) =
      make_ushort4(f2h(ax), f2h(ay), f2h(az), f2h(aw));
  pTg[(size_t)(t * 4 + 0) * 512 + c] = f2h(ax);
  pTg[(size_t)(t * 4 + 1) * 512 + c] = f2h(ay);
  pTg[(size_t)(t * 4 + 2) * 512 + c] = f2h(az);
  pTg[(size_t)(t * 4 + 3) * 512 + c] = f2h(aw);
}

extern "C" void kernel_launch(void* const* d_in, const int* in_sizes, int n_in,
                              void* d_out, int out_size, void* d_ws, size_t ws_size,
                              hipStream_t stream) {
  const float* cls = (const float*)d_in[0];     // [8192,1024]
  const float* proto = (const float*)d_in[1];   // [512,1024]
  float* out_r = (float*)d_out;                 // [8192,512]
  float* out_z = out_r + (size_t)8192 * 512;    // [8192,1024]

  char* w = (char*)d_ws;
  unsigned short* cls_h = (unsigned short*)w; w += (size_t)8192 * 1024 * 2;  // 16 MB
  unsigned short* cls_l = (unsigned short*)w; w += (size_t)8192 * 1024 * 2;  // 16 MB (-> cls fp16 after it1)
  unsigned short* clsT_h = (unsigned short*)w; w += (size_t)1024 * 8192 * 2; // 16 MB
  unsigned short* clsT_l = (unsigned short*)w; w += (size_t)1024 * 8192 * 2; // 16 MB (-> clsT fp16 after it1)
  unsigned short* p_h = (unsigned short*)w; w += (size_t)512 * 1024 * 2;     //  1 MB
  unsigned short* p_l = (unsigned short*)w; w += (size_t)512 * 1024 * 2;     //  1 MB
  unsigned short* p_g = (unsigned short*)w; w += (size_t)512 * 1024 * 2;     //  1 MB (fp16)
  unsigned short* pT_g = (unsigned short*)w; w += (size_t)1024 * 512 * 2;    //  1 MB (fp16)
  unsigned short* rT_h = (unsigned short*)w; w += (size_t)512 * 8192 * 2;    //  8 MB (also fp16 r)
  unsigned short* rT_l = (unsigned short*)w; w += (size_t)512 * 8192 * 2;    //  8 MB
  float* SP = (float*)w;  // 32 MB: [2][512][8192] / [16][512][1024] / [2][8192][512]
  float* SP1 = SP + (size_t)512 * 8192;
  unsigned short* cls_g = cls_l;    // aliases (converted in-place after iter 1)
  unsigned short* clsT_g = clsT_l;

  cast_split_transpose_cls<<<dim3(16, 128), 256, 0, stream>>>(cls, cls_h, cls_l, clsT_h, clsT_l);
  split_f32<<<512, 256, 0, stream>>>(proto, p_h, p_l);

  // EM iteration 1: compensated bf16 (errors here amplify ~2.5^4 through the
  // remaining stages -- iteration 1 is ~62% of the all-bf16 error budget).
  gemm_bt3<<<dim3(64, 4, 2), 256, 0, stream>>>(p_h, p_l, cls_h, cls_l, SP,
                                               8192, 1024, 1024, 512,
                                               (size_t)512 * 8192);
  colsoftmax_fused<false><<<512, 256, 0, stream>>>(SP, SP1, rT_h, rT_l);
  gemm_bt3<<<dim3(8, 4, 16), 256, 0, stream>>>(rT_h, rT_l, clsT_h, clsT_l, SP,
                                               1024, 8192, 8192, 512,
                                               (size_t)512 * 1024);
  // cls_l / clsT_l dead now -> build fp16 cls copies in place.
  fuse_to_f16<<<4096, 256, 0, stream>>>(cls_h, cls_l, cls_g);
  fuse_to_f16<<<4096, 256, 0, stream>>>(clsT_h, clsT_l, clsT_g);
  reduce_normalize<<<512, 256, 0, stream>>>(SP, p_g, pT_g);

  // EM iterations 2-5: plain fp16 (fp16 = bf16/8 error; residual sum ~0.026
  // from round-1's measured 0.545 all-bf16 anchor).
  for (int it = 0; it < 4; ++it) {
    gemm_bt<false, true><<<dim3(64, 4, 2), 256, 0, stream>>>(p_g, cls_g, SP, nullptr,
                                                             8192, 1024, 1024, 512,
                                                             (size_t)512 * 8192);
    colsoftmax_fused<true><<<512, 256, 0, stream>>>(SP, SP1, rT_h, nullptr);
    gemm_bt<false, true><<<dim3(8, 4, 16), 256, 0, stream>>>(rT_h, clsT_g, SP, nullptr,
                                                             1024, 8192, 8192, 512,
                                                             (size_t)512 * 1024);
    reduce_normalize<<<512, 256, 0, stream>>>(SP, p_g, pT_g);
  }

  // Final stage, all fp16: S = cls . p^T, row softmax, z = r @ p + cls.
  gemm_bt<false, true><<<dim3(4, 64, 2), 256, 0, stream>>>(cls_g, p_g, SP, nullptr,
                                                           512, 1024, 1024, 512,
                                                           (size_t)8192 * 512);
  softmax_rows<<<2048, 256, 0, stream>>>(SP, SP + (size_t)8192 * 512, out_r, rT_h);
  gemm_bt<true, true><<<dim3(8, 64, 1), 256, 0, stream>>>(rT_h, pT_g, out_z, cls,
                                                          1024, 512, 512, 512, 0);
}

// Round 7
// 494.617 us; speedup vs baseline: 1.0760x; 1.0760x over previous
//
#include <hip/hip_runtime.h>

typedef short v8s __attribute__((ext_vector_type(8)));
typedef _Float16 v8h __attribute__((ext_vector_type(8)));
typedef float v4f __attribute__((ext_vector_type(4)));

typedef __attribute__((address_space(1))) const void* as1_void_cp;
typedef __attribute__((address_space(3))) void* as3_void_p;

__device__ __forceinline__ unsigned short f2bf(float x) {
  union { float f; unsigned int u; } v; v.f = x;
  unsigned int r = v.u + 0x7fffu + ((v.u >> 16) & 1u);
  return (unsigned short)(r >> 16);
}
__device__ __forceinline__ float bf2f(unsigned short h) {
  union { unsigned int u; float f; } v; v.u = ((unsigned int)h) << 16;
  return v.f;
}
__device__ __forceinline__ unsigned short f2h(float x) {
  _Float16 h = (_Float16)x;  // RTE
  return __builtin_bit_cast(unsigned short, h);
}

// ---------------------------------------------------------------------------
// Plain GEMM (bf16 or fp16 per F16): C[MxN](f32) = A[MxK] @ B[NxK]^T.
// 128x128 tile, BK=64 as two BK=32 sub-tiles (one barrier pair per 64 k —
// halves the vmcnt(0)+barrier drains vs BK=32; LDS pattern per sub-tile is
// the proven m97 layout since global_load_lds forbids padding).
// Split-K via blockIdx.z. klen must be a multiple of 64.
// ---------------------------------------------------------------------------
template <bool ADD, bool F16>
__global__ __launch_bounds__(256) void gemm_bt(
    const unsigned short* __restrict__ A, const unsigned short* __restrict__ B,
    float* __restrict__ C, const float* __restrict__ Cadd,
    int N, int lda, int ldb, int klen, size_t csplit) {
  __shared__ __align__(16) unsigned short As[128 * 64];  // [0..4095]=k0-31, [4096..]=k32-63
  __shared__ __align__(16) unsigned short Bs[128 * 64];
  const int tid = threadIdx.x;
  const int bn = blockIdx.x * 128, bm = blockIdx.y * 128;
  const int k0 = blockIdx.z * klen;
  float* Cp = C + (size_t)blockIdx.z * csplit;

  const unsigned short* ag0 = A + (size_t)(bm + (tid >> 2)) * lda + ((tid & 3) << 3) + k0;
  const unsigned short* ag1 = ag0 + (size_t)64 * lda;
  const unsigned short* bg0 = B + (size_t)(bn + (tid >> 2)) * ldb + ((tid & 3) << 3) + k0;
  const unsigned short* bg1 = bg0 + (size_t)64 * ldb;
  unsigned short* al0 = As + tid * 8;
  unsigned short* al1 = As + 2048 + tid * 8;
  unsigned short* al2 = As + 4096 + tid * 8;
  unsigned short* al3 = As + 6144 + tid * 8;
  unsigned short* bl0 = Bs + tid * 8;
  unsigned short* bl1 = Bs + 2048 + tid * 8;
  unsigned short* bl2 = Bs + 4096 + tid * 8;
  unsigned short* bl3 = Bs + 6144 + tid * 8;

  const int lane = tid & 63;
  const int q = lane >> 4, m15 = lane & 15;
  const int w = tid >> 6;
  const int wr = (w >> 1) * 64, wc = (w & 1) * 64;

  v4f acc[4][4];
#pragma unroll
  for (int i = 0; i < 4; ++i)
#pragma unroll
    for (int j = 0; j < 4; ++j) acc[i][j] = 0.f;

  for (int kk = 0; kk < klen; kk += 64) {
    __builtin_amdgcn_global_load_lds((as1_void_cp)(ag0 + kk), (as3_void_p)al0, 16, 0, 0);
    __builtin_amdgcn_global_load_lds((as1_void_cp)(ag1 + kk), (as3_void_p)al1, 16, 0, 0);
    __builtin_amdgcn_global_load_lds((as1_void_cp)(ag0 + kk + 32), (as3_void_p)al2, 16, 0, 0);
    __builtin_amdgcn_global_load_lds((as1_void_cp)(ag1 + kk + 32), (as3_void_p)al3, 16, 0, 0);
    __builtin_amdgcn_global_load_lds((as1_void_cp)(bg0 + kk), (as3_void_p)bl0, 16, 0, 0);
    __builtin_amdgcn_global_load_lds((as1_void_cp)(bg1 + kk), (as3_void_p)bl1, 16, 0, 0);
    __builtin_amdgcn_global_load_lds((as1_void_cp)(bg0 + kk + 32), (as3_void_p)bl2, 16, 0, 0);
    __builtin_amdgcn_global_load_lds((as1_void_cp)(bg1 + kk + 32), (as3_void_p)bl3, 16, 0, 0);
    __syncthreads();
#pragma unroll
    for (int h = 0; h < 2; ++h) {
      v8s af[4], bf[4];
#pragma unroll
      for (int i = 0; i < 4; ++i)
        af[i] = *(const v8s*)(As + h * 4096 + (wr + i * 16 + m15) * 32 + q * 8);
#pragma unroll
      for (int j = 0; j < 4; ++j)
        bf[j] = *(const v8s*)(Bs + h * 4096 + (wc + j * 16 + m15) * 32 + q * 8);
#pragma unroll
      for (int i = 0; i < 4; ++i)
#pragma unroll
        for (int j = 0; j < 4; ++j) {
          if constexpr (F16)
            acc[i][j] = __builtin_amdgcn_mfma_f32_16x16x32_f16(
                __builtin_bit_cast(v8h, af[i]), __builtin_bit_cast(v8h, bf[j]), acc[i][j], 0, 0, 0);
          else
            acc[i][j] = __builtin_amdgcn_mfma_f32_16x16x32_bf16(af[i], bf[j], acc[i][j], 0, 0, 0);
        }
    }
    __syncthreads();
  }

#pragma unroll
  for (int i = 0; i < 4; ++i) {
#pragma unroll
    for (int j = 0; j < 4; ++j) {
      const int col = bn + wc + j * 16 + m15;
#pragma unroll
      for (int rr = 0; rr < 4; ++rr) {
        const int row = bm + wr + i * 16 + q * 4 + rr;
        const size_t idx = (size_t)row * N + col;
        float v = acc[i][j][rr];
        if (ADD) v += Cadd[idx];
        Cp[idx] = v;
      }
    }
  }
}

// ---------------------------------------------------------------------------
// Split-bf16 (compensated) GEMM: C = (Ah+Al)@(Bh+Bl)^T dropping Al*Bl.
// Used only for EM iteration 1 (largest error amplification). BK=32.
// ---------------------------------------------------------------------------
__global__ __launch_bounds__(256) void gemm_bt3(
    const unsigned short* __restrict__ Ah, const unsigned short* __restrict__ Al,
    const unsigned short* __restrict__ Bh, const unsigned short* __restrict__ Bl,
    float* __restrict__ C, int N, int lda, int ldb, int klen, size_t csplit) {
  __shared__ __align__(16) unsigned short Ash[128 * 32];
  __shared__ __align__(16) unsigned short Asl[128 * 32];
  __shared__ __align__(16) unsigned short Bsh[128 * 32];
  __shared__ __align__(16) unsigned short Bsl[128 * 32];
  const int tid = threadIdx.x;
  const int bn = blockIdx.x * 128, bm = blockIdx.y * 128;
  const int k0 = blockIdx.z * klen;
  float* Cp = C + (size_t)blockIdx.z * csplit;

  const size_t aoff = (size_t)(bm + (tid >> 2)) * lda + ((tid & 3) << 3) + k0;
  const size_t boff = (size_t)(bn + (tid >> 2)) * ldb + ((tid & 3) << 3) + k0;
  const unsigned short* agh0 = Ah + aoff;
  const unsigned short* agh1 = agh0 + (size_t)64 * lda;
  const unsigned short* agl0 = Al + aoff;
  const unsigned short* agl1 = agl0 + (size_t)64 * lda;
  const unsigned short* bgh0 = Bh + boff;
  const unsigned short* bgh1 = bgh0 + (size_t)64 * ldb;
  const unsigned short* bgl0 = Bl + boff;
  const unsigned short* bgl1 = bgl0 + (size_t)64 * ldb;

  const int lane = tid & 63;
  const int q = lane >> 4, m15 = lane & 15;
  const int w = tid >> 6;
  const int wr = (w >> 1) * 64, wc = (w & 1) * 64;

  v4f acc[4][4];
#pragma unroll
  for (int i = 0; i < 4; ++i)
#pragma unroll
    for (int j = 0; j < 4; ++j) acc[i][j] = 0.f;

  for (int kk = 0; kk < klen; kk += 32) {
    __builtin_amdgcn_global_load_lds((as1_void_cp)(agh0 + kk), (as3_void_p)(Ash + tid * 8), 16, 0, 0);
    __builtin_amdgcn_global_load_lds((as1_void_cp)(agh1 + kk), (as3_void_p)(Ash + 2048 + tid * 8), 16, 0, 0);
    __builtin_amdgcn_global_load_lds((as1_void_cp)(agl0 + kk), (as3_void_p)(Asl + tid * 8), 16, 0, 0);
    __builtin_amdgcn_global_load_lds((as1_void_cp)(agl1 + kk), (as3_void_p)(Asl + 2048 + tid * 8), 16, 0, 0);
    __builtin_amdgcn_global_load_lds((as1_void_cp)(bgh0 + kk), (as3_void_p)(Bsh + tid * 8), 16, 0, 0);
    __builtin_amdgcn_global_load_lds((as1_void_cp)(bgh1 + kk), (as3_void_p)(Bsh + 2048 + tid * 8), 16, 0, 0);
    __builtin_amdgcn_global_load_lds((as1_void_cp)(bgl0 + kk), (as3_void_p)(Bsl + tid * 8), 16, 0, 0);
    __builtin_amdgcn_global_load_lds((as1_void_cp)(bgl1 + kk), (as3_void_p)(Bsl + 2048 + tid * 8), 16, 0, 0);
    __syncthreads();
    v8s afh[4], afl[4], bfh[4], bfl[4];
#pragma unroll
    for (int i = 0; i < 4; ++i) {
      const int ro = (wr + i * 16 + m15) * 32 + q * 8;
      afh[i] = *(const v8s*)(Ash + ro);
      afl[i] = *(const v8s*)(Asl + ro);
    }
#pragma unroll
    for (int j = 0; j < 4; ++j) {
      const int ro = (wc + j * 16 + m15) * 32 + q * 8;
      bfh[j] = *(const v8s*)(Bsh + ro);
      bfl[j] = *(const v8s*)(Bsl + ro);
    }
#pragma unroll
    for (int i = 0; i < 4; ++i)
#pragma unroll
      for (int j = 0; j < 4; ++j) {
        acc[i][j] = __builtin_amdgcn_mfma_f32_16x16x32_bf16(afh[i], bfh[j], acc[i][j], 0, 0, 0);
        acc[i][j] = __builtin_amdgcn_mfma_f32_16x16x32_bf16(afh[i], bfl[j], acc[i][j], 0, 0, 0);
        acc[i][j] = __builtin_amdgcn_mfma_f32_16x16x32_bf16(afl[i], bfh[j], acc[i][j], 0, 0, 0);
      }
    __syncthreads();
  }

#pragma unroll
  for (int i = 0; i < 4; ++i) {
#pragma unroll
    for (int j = 0; j < 4; ++j) {
      const int col = bn + wc + j * 16 + m15;
#pragma unroll
      for (int rr = 0; rr < 4; ++rr) {
        const int row = bm + wr + i * 16 + q * 4 + rr;
        Cp[(size_t)row * N + col] = acc[i][j][rr];
      }
    }
  }
}

// cls f32 [8192][1024] -> hi/lo bf16 row-major + hi/lo bf16 transposed
__global__ __launch_bounds__(256) void cast_split_transpose_cls(
    const float* __restrict__ cls,
    unsigned short* __restrict__ ch, unsigned short* __restrict__ cl,
    unsigned short* __restrict__ cTh, unsigned short* __restrict__ cTl) {
  __shared__ unsigned short th[64][72];
  __shared__ unsigned short tl[64][72];
  const int d0 = blockIdx.x * 64, b0 = blockIdx.y * 64;
  const int t = threadIdx.x;
#pragma unroll
  for (int i = 0; i < 4; ++i) {
    int flat = t + i * 256;
    int bl_ = flat >> 4;
    int dl = (flat & 15) << 2;
    float4 v = *(const float4*)(cls + (size_t)(b0 + bl_) * 1024 + d0 + dl);
    ushort4 h, l;
    h.x = f2bf(v.x); l.x = f2bf(v.x - bf2f(h.x));
    h.y = f2bf(v.y); l.y = f2bf(v.y - bf2f(h.y));
    h.z = f2bf(v.z); l.z = f2bf(v.z - bf2f(h.z));
    h.w = f2bf(v.w); l.w = f2bf(v.w - bf2f(h.w));
    *(ushort4*)(ch + (size_t)(b0 + bl_) * 1024 + d0 + dl) = h;
    *(ushort4*)(cl + (size_t)(b0 + bl_) * 1024 + d0 + dl) = l;
    th[bl_][dl] = h.x; th[bl_][dl + 1] = h.y; th[bl_][dl + 2] = h.z; th[bl_][dl + 3] = h.w;
    tl[bl_][dl] = l.x; tl[bl_][dl + 1] = l.y; tl[bl_][dl + 2] = l.z; tl[bl_][dl + 3] = l.w;
  }
  __syncthreads();
#pragma unroll
  for (int i = 0; i < 4; ++i) {
    int flat = t + i * 256;
    int dl = flat >> 4;
    int bl_ = (flat & 15) << 2;
    ushort4 h = make_ushort4(th[bl_][dl], th[bl_ + 1][dl], th[bl_ + 2][dl], th[bl_ + 3][dl]);
    ushort4 l = make_ushort4(tl[bl_][dl], tl[bl_ + 1][dl], tl[bl_ + 2][dl], tl[bl_ + 3][dl]);
    *(ushort4*)(cTh + (size_t)(d0 + dl) * 8192 + b0 + bl_) = h;
    *(ushort4*)(cTl + (size_t)(d0 + dl) * 8192 + b0 + bl_) = l;
  }
}

// f32 -> hi/lo bf16
__global__ __launch_bounds__(256) void split_f32(const float* __restrict__ in,
                                                 unsigned short* __restrict__ hi,
                                                 unsigned short* __restrict__ lo) {
  const size_t i = (size_t)(blockIdx.x * blockDim.x + threadIdx.x) * 4;
  float4 v = *(const float4*)(in + i);
  ushort4 h, l;
  h.x = f2bf(v.x); l.x = f2bf(v.x - bf2f(h.x));
  h.y = f2bf(v.y); l.y = f2bf(v.y - bf2f(h.y));
  h.z = f2bf(v.z); l.z = f2bf(v.z - bf2f(h.z));
  h.w = f2bf(v.w); l.w = f2bf(v.w - bf2f(h.w));
  *(ushort4*)(hi + i) = h;
  *(ushort4*)(lo + i) = l;
}

// bf16 hi+lo -> fp16 for BOTH cls (row-major) and clsT, one dispatch.
// grid 8192: blocks [0,4096) -> set 0, [4096,8192) -> set 1. In-place (out aliases lo).
__global__ __launch_bounds__(256) void fuse_to_f16_dual(
    const unsigned short* __restrict__ h0, const unsigned short* __restrict__ l0,
    unsigned short* __restrict__ o0,
    const unsigned short* __restrict__ h1, const unsigned short* __restrict__ l1,
    unsigned short* __restrict__ o1) {
  const int half = blockIdx.x >> 12;
  const unsigned short* hi = half ? h1 : h0;
  const unsigned short* lo = half ? l1 : l0;
  unsigned short* out = half ? o1 : o0;
  const size_t i = ((size_t)(blockIdx.x & 4095) * 256 + threadIdx.x) * 8;
  ushort4 ha = *(const ushort4*)(hi + i);
  ushort4 hb = *(const ushort4*)(hi + i + 4);
  ushort4 la = *(const ushort4*)(lo + i);
  ushort4 lb = *(const ushort4*)(lo + i + 4);
  ushort4 oa, ob;
  oa.x = f2h(bf2f(ha.x) + bf2f(la.x)); oa.y = f2h(bf2f(ha.y) + bf2f(la.y));
  oa.z = f2h(bf2f(ha.z) + bf2f(la.z)); oa.w = f2h(bf2f(ha.w) + bf2f(la.w));
  ob.x = f2h(bf2f(hb.x) + bf2f(lb.x)); ob.y = f2h(bf2f(hb.y) + bf2f(lb.y));
  ob.z = f2h(bf2f(hb.z) + bf2f(lb.z)); ob.w = f2h(bf2f(hb.w) + bf2f(lb.w));
  *(ushort4*)(out + i) = oa;
  *(ushort4*)(out + i + 4) = ob;
}

__device__ __forceinline__ void online_merge(float& m, float& s, float m2, float s2) {
  float nm = fmaxf(m, m2);
  s = s * __expf(m - nm) + s2 * __expf(m2 - nm);
  m = nm;
}

// Per-column partial (max, sumexp) over a 64-row strip of ST = SP0+SP1.
__global__ __launch_bounds__(256) void colsoftmax_stats(
    const float* __restrict__ SP0, const float* __restrict__ SP1,
    float4* __restrict__ MS) {
  __shared__ float4 red[4][64];
  const int lane = threadIdx.x & 63, w = threadIdx.x >> 6;
  const int b = blockIdx.x * 128 + lane * 2;
  const int c0 = blockIdx.y * 64 + w * 16;
  const float2* x0 = (const float2*)(SP0 + (size_t)c0 * 8192 + b);
  const float2* x1 = (const float2*)(SP1 + (size_t)c0 * 8192 + b);
  float m0 = -3.4e38f, m1 = -3.4e38f, s0 = 0.f, s1 = 0.f;
#pragma unroll
  for (int i = 0; i < 16; ++i) {
    float2 a = x0[(size_t)i * 4096];
    float2 bb = x1[(size_t)i * 4096];
    float v0 = a.x + bb.x, v1 = a.y + bb.y;
    float nm0 = fmaxf(m0, v0);
    s0 = s0 * __expf(m0 - nm0) + __expf(v0 - nm0); m0 = nm0;
    float nm1 = fmaxf(m1, v1);
    s1 = s1 * __expf(m1 - nm1) + __expf(v1 - nm1); m1 = nm1;
  }
  red[w][lane] = make_float4(m0, s0, m1, s1);
  __syncthreads();
  if (w == 0) {
#pragma unroll
    for (int k = 1; k < 4; ++k) {
      float4 r = red[k][lane];
      online_merge(m0, s0, r.x, r.y);
      online_merge(m1, s1, r.z, r.w);
    }
    MS[(size_t)blockIdx.y * 4096 + (b >> 1)] = make_float4(m0, s0, m1, s1);
  }
}

// Combine strip stats, normalize, write rT (bf16 hi/lo, or single fp16).
template <bool F16>
__global__ __launch_bounds__(256) void colsoftmax_write(
    const float* __restrict__ SP0, const float* __restrict__ SP1,
    const float4* __restrict__ MS,
    unsigned short* __restrict__ rh, unsigned short* __restrict__ rl) {
  const int lane = threadIdx.x & 63, w = threadIdx.x >> 6;
  const int b = blockIdx.x * 128 + lane * 2;
  const int c0 = blockIdx.y * 64 + w * 16;
  float m0 = -3.4e38f, m1 = -3.4e38f, s0 = 0.f, s1 = 0.f;
#pragma unroll
  for (int k = 0; k < 8; ++k) {
    float4 r = MS[(size_t)k * 4096 + (b >> 1)];
    online_merge(m0, s0, r.x, r.y);
    online_merge(m1, s1, r.z, r.w);
  }
  const float inv0 = 1.f / s0, inv1 = 1.f / s1;
  const float2* x0 = (const float2*)(SP0 + (size_t)c0 * 8192 + b);
  const float2* x1 = (const float2*)(SP1 + (size_t)c0 * 8192 + b);
#pragma unroll
  for (int i = 0; i < 16; ++i) {
    float2 a = x0[(size_t)i * 4096];
    float2 bb = x1[(size_t)i * 4096];
    float r0 = __expf(a.x + bb.x - m0) * inv0;
    float r1 = __expf(a.y + bb.y - m1) * inv1;
    const size_t idx = (size_t)(c0 + i) * 8192 + b;
    if constexpr (F16) {
      *(ushort2*)(rh + idx) = make_ushort2(f2h(r0), f2h(r1));
    } else {
      unsigned short h0 = f2bf(r0), h1 = f2bf(r1);
      *(ushort2*)(rh + idx) = make_ushort2(h0, h1);
      *(ushort2*)(rl + idx) = make_ushort2(f2bf(r0 - bf2f(h0)), f2bf(r1 - bf2f(h1)));
    }
  }
}

// Final: row softmax of SP0+SP1 [8192][512] -> r f32 (d_out) + r fp16.
__global__ __launch_bounds__(256) void softmax_rows(const float* __restrict__ SP0,
                                                    const float* __restrict__ SP1,
                                                    float* __restrict__ r_out,
                                                    unsigned short* __restrict__ r_g) {
  const int w = threadIdx.x >> 6, lane = threadIdx.x & 63;
  const int row = blockIdx.x * 4 + w;
  const size_t off = (size_t)row * 512 + lane * 8;
  float4 v0 = *(const float4*)(SP0 + off);
  float4 v1 = *(const float4*)(SP0 + off + 4);
  float4 u0 = *(const float4*)(SP1 + off);
  float4 u1 = *(const float4*)(SP1 + off + 4);
  v0.x += u0.x; v0.y += u0.y; v0.z += u0.z; v0.w += u0.w;
  v1.x += u1.x; v1.y += u1.y; v1.z += u1.z; v1.w += u1.w;
  float m = fmaxf(fmaxf(fmaxf(v0.x, v0.y), fmaxf(v0.z, v0.w)),
                  fmaxf(fmaxf(v1.x, v1.y), fmaxf(v1.z, v1.w)));
  for (int off2 = 32; off2; off2 >>= 1) m = fmaxf(m, __shfl_xor(m, off2));
  float e0 = __expf(v0.x - m), e1 = __expf(v0.y - m), e2 = __expf(v0.z - m), e3 = __expf(v0.w - m);
  float e4 = __expf(v1.x - m), e5 = __expf(v1.y - m), e6 = __expf(v1.z - m), e7 = __expf(v1.w - m);
  float s = e0 + e1 + e2 + e3 + e4 + e5 + e6 + e7;
  for (int off2 = 32; off2; off2 >>= 1) s += __shfl_xor(s, off2);
  const float inv = 1.f / s;
  e0 *= inv; e1 *= inv; e2 *= inv; e3 *= inv; e4 *= inv; e5 *= inv; e6 *= inv; e7 *= inv;
  float* rp = r_out + off;
  *(float4*)rp = make_float4(e0, e1, e2, e3);
  *(float4*)(rp + 4) = make_float4(e4, e5, e6, e7);
  unsigned short* bp = r_g + off;
  *(ushort4*)bp = make_ushort4(f2h(e0), f2h(e1), f2h(e2), f2h(e3));
  *(ushort4*)(bp + 4) = make_ushort4(f2h(e4), f2h(e5), f2h(e6), f2h(e7));
}

// Sum 16 split-K partials [512][1024], L2-normalize rows (+1e-6),
// emit p fp16 [512][1024] + pT fp16 [1024][512].
__global__ __launch_bounds__(256) void reduce_normalize(const float* __restrict__ Pp,
                                                        unsigned short* __restrict__ pg,
                                                        unsigned short* __restrict__ pTg) {
  __shared__ float red[4];
  const int c = blockIdx.x, t = threadIdx.x;
  float ax = 0.f, ay = 0.f, az = 0.f, aw = 0.f;
#pragma unroll
  for (int s = 0; s < 16; ++s) {
    const float4 v = *(const float4*)(Pp + ((size_t)s * 512 + c) * 1024 + t * 4);
    ax += v.x; ay += v.y; az += v.z; aw += v.w;
  }
  float ss = ax * ax + ay * ay + az * az + aw * aw;
  for (int off = 32; off; off >>= 1) ss += __shfl_xor(ss, off);
  const int w = t >> 6, lane = t & 63;
  if (!lane) red[w] = ss;
  __syncthreads();
  const float tot = red[0] + red[1] + red[2] + red[3];
  const float scale = 1.f / (sqrtf(tot) + 1e-6f);
  ax *= scale; ay *= scale; az *= scale; aw *= scale;
  *(ushort4*)(pg + (size_t)c * 1024 + t * 4) =
      make_ushort4(f2h(ax), f2h(ay), f2h(az), f2h(aw));
  pTg[(size_t)(t * 4 + 0) * 512 + c] = f2h(ax);
  pTg[(size_t)(t * 4 + 1) * 512 + c] = f2h(ay);
  pTg[(size_t)(t * 4 + 2) * 512 + c] = f2h(az);
  pTg[(size_t)(t * 4 + 3) * 512 + c] = f2h(aw);
}

extern "C" void kernel_launch(void* const* d_in, const int* in_sizes, int n_in,
                              void* d_out, int out_size, void* d_ws, size_t ws_size,
                              hipStream_t stream) {
  const float* cls = (const float*)d_in[0];     // [8192,1024]
  const float* proto = (const float*)d_in[1];   // [512,1024]
  float* out_r = (float*)d_out;                 // [8192,512]
  float* out_z = out_r + (size_t)8192 * 512;    // [8192,1024]

  char* w = (char*)d_ws;
  unsigned short* cls_h = (unsigned short*)w; w += (size_t)8192 * 1024 * 2;  // 16 MB
  unsigned short* cls_l = (unsigned short*)w; w += (size_t)8192 * 1024 * 2;  // 16 MB (-> cls fp16 after it1)
  unsigned short* clsT_h = (unsigned short*)w; w += (size_t)1024 * 8192 * 2; // 16 MB
  unsigned short* clsT_l = (unsigned short*)w; w += (size_t)1024 * 8192 * 2; // 16 MB (-> clsT fp16 after it1)
  unsigned short* p_h = (unsigned short*)w; w += (size_t)512 * 1024 * 2;     //  1 MB
  unsigned short* p_l = (unsigned short*)w; w += (size_t)512 * 1024 * 2;     //  1 MB
  unsigned short* p_g = (unsigned short*)w; w += (size_t)512 * 1024 * 2;     //  1 MB (fp16)
  unsigned short* pT_g = (unsigned short*)w; w += (size_t)1024 * 512 * 2;    //  1 MB (fp16)
  unsigned short* rT_h = (unsigned short*)w; w += (size_t)512 * 8192 * 2;    //  8 MB (also fp16 r)
  unsigned short* rT_l = (unsigned short*)w; w += (size_t)512 * 8192 * 2;    //  8 MB
  float4* MS = (float4*)w; w += (size_t)8 * 4096 * 16;                       // 0.5 MB
  float* SP = (float*)w;  // 32 MB: [2][512][8192] / [16][512][1024] / [2][8192][512]
  float* SP1 = SP + (size_t)512 * 8192;
  unsigned short* cls_g = cls_l;    // aliases (converted in-place after iter 1)
  unsigned short* clsT_g = clsT_l;

  cast_split_transpose_cls<<<dim3(16, 128), 256, 0, stream>>>(cls, cls_h, cls_l, clsT_h, clsT_l);
  split_f32<<<512, 256, 0, stream>>>(proto, p_h, p_l);

  // EM iteration 1: compensated bf16 (errors here amplify ~2.5^4 through the
  // remaining stages -- iteration 1 is ~62% of the all-bf16 error budget).
  gemm_bt3<<<dim3(64, 4, 2), 256, 0, stream>>>(p_h, p_l, cls_h, cls_l, SP,
                                               8192, 1024, 1024, 512,
                                               (size_t)512 * 8192);
  colsoftmax_stats<<<dim3(64, 8), 256, 0, stream>>>(SP, SP1, MS);
  colsoftmax_write<false><<<dim3(64, 8), 256, 0, stream>>>(SP, SP1, MS, rT_h, rT_l);
  gemm_bt3<<<dim3(8, 4, 16), 256, 0, stream>>>(rT_h, rT_l, clsT_h, clsT_l, SP,
                                               1024, 8192, 8192, 512,
                                               (size_t)512 * 1024);
  // cls_l / clsT_l dead now -> build fp16 cls copies in place (one dispatch).
  fuse_to_f16_dual<<<8192, 256, 0, stream>>>(cls_h, cls_l, cls_g, clsT_h, clsT_l, clsT_g);
  reduce_normalize<<<512, 256, 0, stream>>>(SP, p_g, pT_g);

  // EM iterations 2-5: plain fp16 (fp16 = bf16/8 error; residual sum ~0.026
  // from round-1's measured 0.545 all-bf16 anchor).
  for (int it = 0; it < 4; ++it) {
    gemm_bt<false, true><<<dim3(64, 4, 2), 256, 0, stream>>>(p_g, cls_g, SP, nullptr,
                                                             8192, 1024, 1024, 512,
                                                             (size_t)512 * 8192);
    colsoftmax_stats<<<dim3(64, 8), 256, 0, stream>>>(SP, SP1, MS);
    colsoftmax_write<true><<<dim3(64, 8), 256, 0, stream>>>(SP, SP1, MS, rT_h, nullptr);
    gemm_bt<false, true><<<dim3(8, 4, 16), 256, 0, stream>>>(rT_h, clsT_g, SP, nullptr,
                                                             1024, 8192, 8192, 512,
                                                             (size_t)512 * 1024);
    reduce_normalize<<<512, 256, 0, stream>>>(SP, p_g, pT_g);
  }

  // Final stage, all fp16: S = cls . p^T, row softmax, z = r @ p + cls.
  gemm_bt<false, true><<<dim3(4, 64, 2), 256, 0, stream>>>(cls_g, p_g, SP, nullptr,
                                                           512, 1024, 1024, 512,
                                                           (size_t)8192 * 512);
  softmax_rows<<<2048, 256, 0, stream>>>(SP, SP + (size_t)8192 * 512, out_r, rT_h);
  gemm_bt<true, true><<<dim3(8, 64, 1), 256, 0, stream>>>(rT_h, pT_g, out_z, cls,
                                                          1024, 512, 512, 512, 0);
}

// Round 8
// 487.022 us; speedup vs baseline: 1.0928x; 1.0156x over previous
//
#include <hip/hip_runtime.h>

typedef short v8s __attribute__((ext_vector_type(8)));
typedef _Float16 v8h __attribute__((ext_vector_type(8)));
typedef float v4f __attribute__((ext_vector_type(4)));

typedef __attribute__((address_space(1))) const void* as1_void_cp;
typedef __attribute__((address_space(3))) void* as3_void_p;

__device__ __forceinline__ unsigned short f2bf(float x) {
  union { float f; unsigned int u; } v; v.f = x;
  unsigned int r = v.u + 0x7fffu + ((v.u >> 16) & 1u);
  return (unsigned short)(r >> 16);
}
__device__ __forceinline__ float bf2f(unsigned short h) {
  union { unsigned int u; float f; } v; v.u = ((unsigned int)h) << 16;
  return v.f;
}
__device__ __forceinline__ unsigned short f2h(float x) {
  _Float16 h = (_Float16)x;  // RTE
  return __builtin_bit_cast(unsigned short, h);
}

// ---------------------------------------------------------------------------
// Plain GEMM (bf16 or fp16 per F16): C[MxN](f32) = A[MxK] @ B[NxK]^T.
// 128x128 tile, BK=64 as two BK=32 sub-tiles (one barrier pair per 64 k).
// Split-K via blockIdx.z. klen must be a multiple of 64.
// ---------------------------------------------------------------------------
template <bool ADD, bool F16>
__global__ __launch_bounds__(256) void gemm_bt(
    const unsigned short* __restrict__ A, const unsigned short* __restrict__ B,
    float* __restrict__ C, const float* __restrict__ Cadd,
    int N, int lda, int ldb, int klen, size_t csplit) {
  __shared__ __align__(16) unsigned short As[128 * 64];
  __shared__ __align__(16) unsigned short Bs[128 * 64];
  const int tid = threadIdx.x;
  const int bn = blockIdx.x * 128, bm = blockIdx.y * 128;
  const int k0 = blockIdx.z * klen;
  float* Cp = C + (size_t)blockIdx.z * csplit;

  const unsigned short* ag0 = A + (size_t)(bm + (tid >> 2)) * lda + ((tid & 3) << 3) + k0;
  const unsigned short* ag1 = ag0 + (size_t)64 * lda;
  const unsigned short* bg0 = B + (size_t)(bn + (tid >> 2)) * ldb + ((tid & 3) << 3) + k0;
  const unsigned short* bg1 = bg0 + (size_t)64 * ldb;
  unsigned short* al0 = As + tid * 8;
  unsigned short* al1 = As + 2048 + tid * 8;
  unsigned short* al2 = As + 4096 + tid * 8;
  unsigned short* al3 = As + 6144 + tid * 8;
  unsigned short* bl0 = Bs + tid * 8;
  unsigned short* bl1 = Bs + 2048 + tid * 8;
  unsigned short* bl2 = Bs + 4096 + tid * 8;
  unsigned short* bl3 = Bs + 6144 + tid * 8;

  const int lane = tid & 63;
  const int q = lane >> 4, m15 = lane & 15;
  const int w = tid >> 6;
  const int wr = (w >> 1) * 64, wc = (w & 1) * 64;

  v4f acc[4][4];
#pragma unroll
  for (int i = 0; i < 4; ++i)
#pragma unroll
    for (int j = 0; j < 4; ++j) acc[i][j] = 0.f;

  for (int kk = 0; kk < klen; kk += 64) {
    __builtin_amdgcn_global_load_lds((as1_void_cp)(ag0 + kk), (as3_void_p)al0, 16, 0, 0);
    __builtin_amdgcn_global_load_lds((as1_void_cp)(ag1 + kk), (as3_void_p)al1, 16, 0, 0);
    __builtin_amdgcn_global_load_lds((as1_void_cp)(ag0 + kk + 32), (as3_void_p)al2, 16, 0, 0);
    __builtin_amdgcn_global_load_lds((as1_void_cp)(ag1 + kk + 32), (as3_void_p)al3, 16, 0, 0);
    __builtin_amdgcn_global_load_lds((as1_void_cp)(bg0 + kk), (as3_void_p)bl0, 16, 0, 0);
    __builtin_amdgcn_global_load_lds((as1_void_cp)(bg1 + kk), (as3_void_p)bl1, 16, 0, 0);
    __builtin_amdgcn_global_load_lds((as1_void_cp)(bg0 + kk + 32), (as3_void_p)bl2, 16, 0, 0);
    __builtin_amdgcn_global_load_lds((as1_void_cp)(bg1 + kk + 32), (as3_void_p)bl3, 16, 0, 0);
    __syncthreads();
#pragma unroll
    for (int h = 0; h < 2; ++h) {
      v8s af[4], bf[4];
#pragma unroll
      for (int i = 0; i < 4; ++i)
        af[i] = *(const v8s*)(As + h * 4096 + (wr + i * 16 + m15) * 32 + q * 8);
#pragma unroll
      for (int j = 0; j < 4; ++j)
        bf[j] = *(const v8s*)(Bs + h * 4096 + (wc + j * 16 + m15) * 32 + q * 8);
#pragma unroll
      for (int i = 0; i < 4; ++i)
#pragma unroll
        for (int j = 0; j < 4; ++j) {
          if constexpr (F16)
            acc[i][j] = __builtin_amdgcn_mfma_f32_16x16x32_f16(
                __builtin_bit_cast(v8h, af[i]), __builtin_bit_cast(v8h, bf[j]), acc[i][j], 0, 0, 0);
          else
            acc[i][j] = __builtin_amdgcn_mfma_f32_16x16x32_bf16(af[i], bf[j], acc[i][j], 0, 0, 0);
        }
    }
    __syncthreads();
  }

#pragma unroll
  for (int i = 0; i < 4; ++i) {
#pragma unroll
    for (int j = 0; j < 4; ++j) {
      const int col = bn + wc + j * 16 + m15;
#pragma unroll
      for (int rr = 0; rr < 4; ++rr) {
        const int row = bm + wr + i * 16 + q * 4 + rr;
        const size_t idx = (size_t)row * N + col;
        float v = acc[i][j][rr];
        if (ADD) v += Cadd[idx];
        Cp[idx] = v;
      }
    }
  }
}

// ---------------------------------------------------------------------------
// Split-bf16 (compensated) GEMM: C = (Ah+Al)@(Bh+Bl)^T dropping Al*Bl.
// Used only for EM iteration 1 (largest error amplification). BK=32.
// ---------------------------------------------------------------------------
__global__ __launch_bounds__(256) void gemm_bt3(
    const unsigned short* __restrict__ Ah, const unsigned short* __restrict__ Al,
    const unsigned short* __restrict__ Bh, const unsigned short* __restrict__ Bl,
    float* __restrict__ C, int N, int lda, int ldb, int klen, size_t csplit) {
  __shared__ __align__(16) unsigned short Ash[128 * 32];
  __shared__ __align__(16) unsigned short Asl[128 * 32];
  __shared__ __align__(16) unsigned short Bsh[128 * 32];
  __shared__ __align__(16) unsigned short Bsl[128 * 32];
  const int tid = threadIdx.x;
  const int bn = blockIdx.x * 128, bm = blockIdx.y * 128;
  const int k0 = blockIdx.z * klen;
  float* Cp = C + (size_t)blockIdx.z * csplit;

  const size_t aoff = (size_t)(bm + (tid >> 2)) * lda + ((tid & 3) << 3) + k0;
  const size_t boff = (size_t)(bn + (tid >> 2)) * ldb + ((tid & 3) << 3) + k0;
  const unsigned short* agh0 = Ah + aoff;
  const unsigned short* agh1 = agh0 + (size_t)64 * lda;
  const unsigned short* agl0 = Al + aoff;
  const unsigned short* agl1 = agl0 + (size_t)64 * lda;
  const unsigned short* bgh0 = Bh + boff;
  const unsigned short* bgh1 = bgh0 + (size_t)64 * ldb;
  const unsigned short* bgl0 = Bl + boff;
  const unsigned short* bgl1 = bgl0 + (size_t)64 * ldb;

  const int lane = tid & 63;
  const int q = lane >> 4, m15 = lane & 15;
  const int w = tid >> 6;
  const int wr = (w >> 1) * 64, wc = (w & 1) * 64;

  v4f acc[4][4];
#pragma unroll
  for (int i = 0; i < 4; ++i)
#pragma unroll
    for (int j = 0; j < 4; ++j) acc[i][j] = 0.f;

  for (int kk = 0; kk < klen; kk += 32) {
    __builtin_amdgcn_global_load_lds((as1_void_cp)(agh0 + kk), (as3_void_p)(Ash + tid * 8), 16, 0, 0);
    __builtin_amdgcn_global_load_lds((as1_void_cp)(agh1 + kk), (as3_void_p)(Ash + 2048 + tid * 8), 16, 0, 0);
    __builtin_amdgcn_global_load_lds((as1_void_cp)(agl0 + kk), (as3_void_p)(Asl + tid * 8), 16, 0, 0);
    __builtin_amdgcn_global_load_lds((as1_void_cp)(agl1 + kk), (as3_void_p)(Asl + 2048 + tid * 8), 16, 0, 0);
    __builtin_amdgcn_global_load_lds((as1_void_cp)(bgh0 + kk), (as3_void_p)(Bsh + tid * 8), 16, 0, 0);
    __builtin_amdgcn_global_load_lds((as1_void_cp)(bgh1 + kk), (as3_void_p)(Bsh + 2048 + tid * 8), 16, 0, 0);
    __builtin_amdgcn_global_load_lds((as1_void_cp)(bgl0 + kk), (as3_void_p)(Bsl + tid * 8), 16, 0, 0);
    __builtin_amdgcn_global_load_lds((as1_void_cp)(bgl1 + kk), (as3_void_p)(Bsl + 2048 + tid * 8), 16, 0, 0);
    __syncthreads();
    v8s afh[4], afl[4], bfh[4], bfl[4];
#pragma unroll
    for (int i = 0; i < 4; ++i) {
      const int ro = (wr + i * 16 + m15) * 32 + q * 8;
      afh[i] = *(const v8s*)(Ash + ro);
      afl[i] = *(const v8s*)(Asl + ro);
    }
#pragma unroll
    for (int j = 0; j < 4; ++j) {
      const int ro = (wc + j * 16 + m15) * 32 + q * 8;
      bfh[j] = *(const v8s*)(Bsh + ro);
      bfl[j] = *(const v8s*)(Bsl + ro);
    }
#pragma unroll
    for (int i = 0; i < 4; ++i)
#pragma unroll
      for (int j = 0; j < 4; ++j) {
        acc[i][j] = __builtin_amdgcn_mfma_f32_16x16x32_bf16(afh[i], bfh[j], acc[i][j], 0, 0, 0);
        acc[i][j] = __builtin_amdgcn_mfma_f32_16x16x32_bf16(afh[i], bfl[j], acc[i][j], 0, 0, 0);
        acc[i][j] = __builtin_amdgcn_mfma_f32_16x16x32_bf16(afl[i], bfh[j], acc[i][j], 0, 0, 0);
      }
    __syncthreads();
  }

#pragma unroll
  for (int i = 0; i < 4; ++i) {
#pragma unroll
    for (int j = 0; j < 4; ++j) {
      const int col = bn + wc + j * 16 + m15;
#pragma unroll
      for (int rr = 0; rr < 4; ++rr) {
        const int row = bm + wr + i * 16 + q * 4 + rr;
        Cp[(size_t)row * N + col] = acc[i][j][rr];
      }
    }
  }
}

// cls f32 [8192][1024] -> hi/lo bf16 row-major + hi/lo bf16 transposed
__global__ __launch_bounds__(256) void cast_split_transpose_cls(
    const float* __restrict__ cls,
    unsigned short* __restrict__ ch, unsigned short* __restrict__ cl,
    unsigned short* __restrict__ cTh, unsigned short* __restrict__ cTl) {
  __shared__ unsigned short th[64][72];
  __shared__ unsigned short tl[64][72];
  const int d0 = blockIdx.x * 64, b0 = blockIdx.y * 64;
  const int t = threadIdx.x;
#pragma unroll
  for (int i = 0; i < 4; ++i) {
    int flat = t + i * 256;
    int bl_ = flat >> 4;
    int dl = (flat & 15) << 2;
    float4 v = *(const float4*)(cls + (size_t)(b0 + bl_) * 1024 + d0 + dl);
    ushort4 h, l;
    h.x = f2bf(v.x); l.x = f2bf(v.x - bf2f(h.x));
    h.y = f2bf(v.y); l.y = f2bf(v.y - bf2f(h.y));
    h.z = f2bf(v.z); l.z = f2bf(v.z - bf2f(h.z));
    h.w = f2bf(v.w); l.w = f2bf(v.w - bf2f(h.w));
    *(ushort4*)(ch + (size_t)(b0 + bl_) * 1024 + d0 + dl) = h;
    *(ushort4*)(cl + (size_t)(b0 + bl_) * 1024 + d0 + dl) = l;
    th[bl_][dl] = h.x; th[bl_][dl + 1] = h.y; th[bl_][dl + 2] = h.z; th[bl_][dl + 3] = h.w;
    tl[bl_][dl] = l.x; tl[bl_][dl + 1] = l.y; tl[bl_][dl + 2] = l.z; tl[bl_][dl + 3] = l.w;
  }
  __syncthreads();
#pragma unroll
  for (int i = 0; i < 4; ++i) {
    int flat = t + i * 256;
    int dl = flat >> 4;
    int bl_ = (flat & 15) << 2;
    ushort4 h = make_ushort4(th[bl_][dl], th[bl_ + 1][dl], th[bl_ + 2][dl], th[bl_ + 3][dl]);
    ushort4 l = make_ushort4(tl[bl_][dl], tl[bl_ + 1][dl], tl[bl_ + 2][dl], tl[bl_ + 3][dl]);
    *(ushort4*)(cTh + (size_t)(d0 + dl) * 8192 + b0 + bl_) = h;
    *(ushort4*)(cTl + (size_t)(d0 + dl) * 8192 + b0 + bl_) = l;
  }
}

// f32 -> hi/lo bf16
__global__ __launch_bounds__(256) void split_f32(const float* __restrict__ in,
                                                 unsigned short* __restrict__ hi,
                                                 unsigned short* __restrict__ lo) {
  const size_t i = (size_t)(blockIdx.x * blockDim.x + threadIdx.x) * 4;
  float4 v = *(const float4*)(in + i);
  ushort4 h, l;
  h.x = f2bf(v.x); l.x = f2bf(v.x - bf2f(h.x));
  h.y = f2bf(v.y); l.y = f2bf(v.y - bf2f(h.y));
  h.z = f2bf(v.z); l.z = f2bf(v.z - bf2f(h.z));
  h.w = f2bf(v.w); l.w = f2bf(v.w - bf2f(h.w));
  *(ushort4*)(hi + i) = h;
  *(ushort4*)(lo + i) = l;
}

// bf16 hi+lo -> fp16 for BOTH cls (row-major) and clsT, one dispatch.
__global__ __launch_bounds__(256) void fuse_to_f16_dual(
    const unsigned short* __restrict__ h0, const unsigned short* __restrict__ l0,
    unsigned short* __restrict__ o0,
    const unsigned short* __restrict__ h1, const unsigned short* __restrict__ l1,
    unsigned short* __restrict__ o1) {
  const int half = blockIdx.x >> 12;
  const unsigned short* hi = half ? h1 : h0;
  const unsigned short* lo = half ? l1 : l0;
  unsigned short* out = half ? o1 : o0;
  const size_t i = ((size_t)(blockIdx.x & 4095) * 256 + threadIdx.x) * 8;
  ushort4 ha = *(const ushort4*)(hi + i);
  ushort4 hb = *(const ushort4*)(hi + i + 4);
  ushort4 la = *(const ushort4*)(lo + i);
  ushort4 lb = *(const ushort4*)(lo + i + 4);
  ushort4 oa, ob;
  oa.x = f2h(bf2f(ha.x) + bf2f(la.x)); oa.y = f2h(bf2f(ha.y) + bf2f(la.y));
  oa.z = f2h(bf2f(ha.z) + bf2f(la.z)); oa.w = f2h(bf2f(ha.w) + bf2f(la.w));
  ob.x = f2h(bf2f(hb.x) + bf2f(lb.x)); ob.y = f2h(bf2f(hb.y) + bf2f(lb.y));
  ob.z = f2h(bf2f(hb.z) + bf2f(lb.z)); ob.w = f2h(bf2f(hb.w) + bf2f(lb.w));
  *(ushort4*)(out + i) = oa;
  *(ushort4*)(out + i + 4) = ob;
}

// ---------------------------------------------------------------------------
// Fused row-softmax + transpose: S = SP0+SP1 ([b=8192][c=512] f32, split-K
// partials), row softmax over c, write rT ([c=512][b=8192]).
// HILO: bf16 hi/lo pair (iter 1); else single fp16.
// Block: 512 thr (8 waves), 32 b-rows; wave-per-row shfl softmax; transpose
// via padded LDS tile; write-out = one full 64B line per c-row per block.
// ---------------------------------------------------------------------------
template <bool HILO>
__global__ __launch_bounds__(512) void rowsoftmax_T(
    const float* __restrict__ SP0, const float* __restrict__ SP1,
    unsigned short* __restrict__ rTh, unsigned short* __restrict__ rTl) {
  __shared__ __align__(16) unsigned short th[32 * 520];
  __shared__ __align__(16) unsigned short tl[HILO ? 32 * 520 : 8];
  const int t = threadIdx.x;
  const int lane = t & 63, w = t >> 6;
  const int b0 = blockIdx.x * 32;
#pragma unroll
  for (int k = 0; k < 4; ++k) {
    const int bl = w * 4 + k;
    const int row = b0 + bl;
    const size_t off = (size_t)row * 512 + lane * 8;
    float4 v0 = *(const float4*)(SP0 + off);
    float4 v1 = *(const float4*)(SP0 + off + 4);
    float4 u0 = *(const float4*)(SP1 + off);
    float4 u1 = *(const float4*)(SP1 + off + 4);
    float e[8];
    e[0] = v0.x + u0.x; e[1] = v0.y + u0.y; e[2] = v0.z + u0.z; e[3] = v0.w + u0.w;
    e[4] = v1.x + u1.x; e[5] = v1.y + u1.y; e[6] = v1.z + u1.z; e[7] = v1.w + u1.w;
    float m = fmaxf(fmaxf(fmaxf(e[0], e[1]), fmaxf(e[2], e[3])),
                    fmaxf(fmaxf(e[4], e[5]), fmaxf(e[6], e[7])));
    for (int o = 32; o; o >>= 1) m = fmaxf(m, __shfl_xor(m, o));
    float s = 0.f;
#pragma unroll
    for (int i = 0; i < 8; ++i) { e[i] = __expf(e[i] - m); s += e[i]; }
    for (int o = 32; o; o >>= 1) s += __shfl_xor(s, o);
    const float inv = 1.f / s;
    unsigned short ph[8], pl[8];
#pragma unroll
    for (int i = 0; i < 8; ++i) {
      const float r = e[i] * inv;
      if constexpr (HILO) {
        ph[i] = f2bf(r);
        pl[i] = f2bf(r - bf2f(ph[i]));
      } else {
        ph[i] = f2h(r);
      }
    }
    *(v8s*)&th[bl * 520 + lane * 8] = *(v8s*)ph;
    if constexpr (HILO) *(v8s*)&tl[bl * 520 + lane * 8] = *(v8s*)pl;
  }
  __syncthreads();
  // write-out: thread t owns c-row t; 32 b values -> one 64B contiguous chunk
  const int c = t;
  unsigned short uh[32];
#pragma unroll
  for (int b = 0; b < 32; ++b) uh[b] = th[b * 520 + c];
#pragma unroll
  for (int q = 0; q < 4; ++q)
    *(v8s*)(rTh + (size_t)c * 8192 + b0 + q * 8) = *(v8s*)&uh[q * 8];
  if constexpr (HILO) {
    unsigned short ul[32];
#pragma unroll
    for (int b = 0; b < 32; ++b) ul[b] = tl[b * 520 + c];
#pragma unroll
    for (int q = 0; q < 4; ++q)
      *(v8s*)(rTl + (size_t)c * 8192 + b0 + q * 8) = *(v8s*)&ul[q * 8];
  }
}

// Final: row softmax of SP0+SP1 [8192][512] -> r f32 (d_out) + r fp16 row-major.
__global__ __launch_bounds__(256) void softmax_rows(const float* __restrict__ SP0,
                                                    const float* __restrict__ SP1,
                                                    float* __restrict__ r_out,
                                                    unsigned short* __restrict__ r_g) {
  const int w = threadIdx.x >> 6, lane = threadIdx.x & 63;
  const int row = blockIdx.x * 4 + w;
  const size_t off = (size_t)row * 512 + lane * 8;
  float4 v0 = *(const float4*)(SP0 + off);
  float4 v1 = *(const float4*)(SP0 + off + 4);
  float4 u0 = *(const float4*)(SP1 + off);
  float4 u1 = *(const float4*)(SP1 + off + 4);
  v0.x += u0.x; v0.y += u0.y; v0.z += u0.z; v0.w += u0.w;
  v1.x += u1.x; v1.y += u1.y; v1.z += u1.z; v1.w += u1.w;
  float m = fmaxf(fmaxf(fmaxf(v0.x, v0.y), fmaxf(v0.z, v0.w)),
                  fmaxf(fmaxf(v1.x, v1.y), fmaxf(v1.z, v1.w)));
  for (int off2 = 32; off2; off2 >>= 1) m = fmaxf(m, __shfl_xor(m, off2));
  float e0 = __expf(v0.x - m), e1 = __expf(v0.y - m), e2 = __expf(v0.z - m), e3 = __expf(v0.w - m);
  float e4 = __expf(v1.x - m), e5 = __expf(v1.y - m), e6 = __expf(v1.z - m), e7 = __expf(v1.w - m);
  float s = e0 + e1 + e2 + e3 + e4 + e5 + e6 + e7;
  for (int off2 = 32; off2; off2 >>= 1) s += __shfl_xor(s, off2);
  const float inv = 1.f / s;
  e0 *= inv; e1 *= inv; e2 *= inv; e3 *= inv; e4 *= inv; e5 *= inv; e6 *= inv; e7 *= inv;
  float* rp = r_out + off;
  *(float4*)rp = make_float4(e0, e1, e2, e3);
  *(float4*)(rp + 4) = make_float4(e4, e5, e6, e7);
  unsigned short* bp = r_g + off;
  *(ushort4*)bp = make_ushort4(f2h(e0), f2h(e1), f2h(e2), f2h(e3));
  *(ushort4*)(bp + 4) = make_ushort4(f2h(e4), f2h(e5), f2h(e6), f2h(e7));
}

// Sum 16 split-K partials [512][1024], L2-normalize rows (+1e-6),
// emit p fp16 [512][1024] + pT fp16 [1024][512].
__global__ __launch_bounds__(256) void reduce_normalize(const float* __restrict__ Pp,
                                                        unsigned short* __restrict__ pg,
                                                        unsigned short* __restrict__ pTg) {
  __shared__ float red[4];
  const int c = blockIdx.x, t = threadIdx.x;
  float ax = 0.f, ay = 0.f, az = 0.f, aw = 0.f;
#pragma unroll
  for (int s = 0; s < 16; ++s) {
    const float4 v = *(const float4*)(Pp + ((size_t)s * 512 + c) * 1024 + t * 4);
    ax += v.x; ay += v.y; az += v.z; aw += v.w;
  }
  float ss = ax * ax + ay * ay + az * az + aw * aw;
  for (int off = 32; off; off >>= 1) ss += __shfl_xor(ss, off);
  const int w = t >> 6, lane = t & 63;
  if (!lane) red[w] = ss;
  __syncthreads();
  const float tot = red[0] + red[1] + red[2] + red[3];
  const float scale = 1.f / (sqrtf(tot) + 1e-6f);
  ax *= scale; ay *= scale; az *= scale; aw *= scale;
  *(ushort4*)(pg + (size_t)c * 1024 + t * 4) =
      make_ushort4(f2h(ax), f2h(ay), f2h(az), f2h(aw));
  pTg[(size_t)(t * 4 + 0) * 512 + c] = f2h(ax);
  pTg[(size_t)(t * 4 + 1) * 512 + c] = f2h(ay);
  pTg[(size_t)(t * 4 + 2) * 512 + c] = f2h(az);
  pTg[(size_t)(t * 4 + 3) * 512 + c] = f2h(aw);
}

// Same for compensated iter-1 path: emit p hi/lo bf16 + pT hi/lo isn't needed
// (stage-1 uses row-major p only); emit p_h/p_l.
__global__ __launch_bounds__(256) void reduce_normalize_hl(const float* __restrict__ Pp,
                                                           unsigned short* __restrict__ ph,
                                                           unsigned short* __restrict__ pl) {
  __shared__ float red[4];
  const int c = blockIdx.x, t = threadIdx.x;
  float ax = 0.f, ay = 0.f, az = 0.f, aw = 0.f;
#pragma unroll
  for (int s = 0; s < 16; ++s) {
    const float4 v = *(const float4*)(Pp + ((size_t)s * 512 + c) * 1024 + t * 4);
    ax += v.x; ay += v.y; az += v.z; aw += v.w;
  }
  float ss = ax * ax + ay * ay + az * az + aw * aw;
  for (int off = 32; off; off >>= 1) ss += __shfl_xor(ss, off);
  const int w = t >> 6, lane = t & 63;
  if (!lane) red[w] = ss;
  __syncthreads();
  const float tot = red[0] + red[1] + red[2] + red[3];
  const float scale = 1.f / (sqrtf(tot) + 1e-6f);
  ax *= scale; ay *= scale; az *= scale; aw *= scale;
  ushort4 h, l;
  h.x = f2bf(ax); l.x = f2bf(ax - bf2f(h.x));
  h.y = f2bf(ay); l.y = f2bf(ay - bf2f(h.y));
  h.z = f2bf(az); l.z = f2bf(az - bf2f(h.z));
  h.w = f2bf(aw); l.w = f2bf(aw - bf2f(h.w));
  *(ushort4*)(ph + (size_t)c * 1024 + t * 4) = h;
  *(ushort4*)(pl + (size_t)c * 1024 + t * 4) = l;
}

extern "C" void kernel_launch(void* const* d_in, const int* in_sizes, int n_in,
                              void* d_out, int out_size, void* d_ws, size_t ws_size,
                              hipStream_t stream) {
  const float* cls = (const float*)d_in[0];     // [8192,1024]
  const float* proto = (const float*)d_in[1];   // [512,1024]
  float* out_r = (float*)d_out;                 // [8192,512]
  float* out_z = out_r + (size_t)8192 * 512;    // [8192,1024]

  char* w = (char*)d_ws;
  unsigned short* cls_h = (unsigned short*)w; w += (size_t)8192 * 1024 * 2;  // 16 MB
  unsigned short* cls_l = (unsigned short*)w; w += (size_t)8192 * 1024 * 2;  // 16 MB (-> cls fp16 after it1)
  unsigned short* clsT_h = (unsigned short*)w; w += (size_t)1024 * 8192 * 2; // 16 MB
  unsigned short* clsT_l = (unsigned short*)w; w += (size_t)1024 * 8192 * 2; // 16 MB (-> clsT fp16 after it1)
  unsigned short* p_h = (unsigned short*)w; w += (size_t)512 * 1024 * 2;     //  1 MB
  unsigned short* p_l = (unsigned short*)w; w += (size_t)512 * 1024 * 2;     //  1 MB
  unsigned short* p_g = (unsigned short*)w; w += (size_t)512 * 1024 * 2;     //  1 MB (fp16)
  unsigned short* pT_g = (unsigned short*)w; w += (size_t)1024 * 512 * 2;    //  1 MB (fp16)
  unsigned short* rT_h = (unsigned short*)w; w += (size_t)512 * 8192 * 2;    //  8 MB (also fp16 r)
  unsigned short* rT_l = (unsigned short*)w; w += (size_t)512 * 8192 * 2;    //  8 MB
  float* SP = (float*)w;  // 32 MB: [2][8192][512] / [16][512][1024]
  float* SP1 = SP + (size_t)8192 * 512;
  unsigned short* cls_g = cls_l;    // aliases (converted in-place after iter 1)
  unsigned short* clsT_g = clsT_l;

  cast_split_transpose_cls<<<dim3(16, 128), 256, 0, stream>>>(cls, cls_h, cls_l, clsT_h, clsT_l);
  split_f32<<<512, 256, 0, stream>>>(proto, p_h, p_l);

  // EM iteration 1: compensated bf16, row-major orientation.
  // S[b][c] = cls . p  (M=8192, N=512, K=1024, split-K=2)
  gemm_bt3<<<dim3(4, 64, 2), 256, 0, stream>>>(cls_h, cls_l, p_h, p_l, SP,
                                               512, 1024, 1024, 512,
                                               (size_t)8192 * 512);
  rowsoftmax_T<true><<<256, 512, 0, stream>>>(SP, SP1, rT_h, rT_l);
  // P[c][d] = sum_b r[b][c] cls[b][d]  (M=512, N=1024, K=8192, split-K=16)
  gemm_bt3<<<dim3(8, 4, 16), 256, 0, stream>>>(rT_h, rT_l, clsT_h, clsT_l, SP,
                                               1024, 8192, 8192, 512,
                                               (size_t)512 * 1024);
  // cls_l / clsT_l dead now -> build fp16 cls copies in place (one dispatch).
  fuse_to_f16_dual<<<8192, 256, 0, stream>>>(cls_h, cls_l, cls_g, clsT_h, clsT_l, clsT_g);
  reduce_normalize<<<512, 256, 0, stream>>>(SP, p_g, pT_g);

  // EM iterations 2-5: plain fp16.
  for (int it = 0; it < 4; ++it) {
    gemm_bt<false, true><<<dim3(4, 64, 2), 256, 0, stream>>>(cls_g, p_g, SP, nullptr,
                                                             512, 1024, 1024, 512,
                                                             (size_t)8192 * 512);
    rowsoftmax_T<false><<<256, 512, 0, stream>>>(SP, SP1, rT_h, nullptr);
    gemm_bt<false, true><<<dim3(8, 4, 16), 256, 0, stream>>>(rT_h, clsT_g, SP, nullptr,
                                                             1024, 8192, 8192, 512,
                                                             (size_t)512 * 1024);
    reduce_normalize<<<512, 256, 0, stream>>>(SP, p_g, pT_g);
  }

  // Final stage, all fp16: S = cls . p^T, row softmax, z = r @ p + cls.
  gemm_bt<false, true><<<dim3(4, 64, 2), 256, 0, stream>>>(cls_g, p_g, SP, nullptr,
                                                           512, 1024, 1024, 512,
                                                           (size_t)8192 * 512);
  softmax_rows<<<2048, 256, 0, stream>>>(SP, SP1, out_r, rT_h);
  gemm_bt<true, true><<<dim3(8, 64, 1), 256, 0, stream>>>(rT_h, pT_g, out_z, cls,
                                                          1024, 512, 512, 512, 0);
}